// Round 12
// baseline (398.558 us; speedup 1.0000x reference)
//
#include <hip/hip_runtime.h>
#include <hip/hip_bf16.h>

// Shapes: B=2, L=1024, D_MODEL=1024, D_INNER=2048, D_STATE=16, D_CONV=4, DT_RANK=64
#define BATCH 2
#define SEQLEN 1024
#define DMODEL 1024
#define DINNER 2048
#define DSTATE 16
#define DTRANK 64
#define ROWS (BATCH * SEQLEN) // 2048
#define LOG2E 1.44269504088896340736f

using bf16 = __hip_bfloat16;
typedef __bf16 bf16x8 __attribute__((ext_vector_type(8)));
typedef float f32x4 __attribute__((ext_vector_type(4)));
typedef unsigned short us8 __attribute__((ext_vector_type(8)));

__device__ __forceinline__ float to_f(float x) { return x; }
__device__ __forceinline__ float to_f(bf16 x) { return __bfloat162float(x); }

__device__ __forceinline__ float fexp2(float x) { return __builtin_amdgcn_exp2f(x); }

__device__ __forceinline__ float bfu(unsigned short u) {
    union { unsigned int i; float f; } v;
    v.i = ((unsigned int)u) << 16;
    return v.f;
}

__device__ __forceinline__ unsigned short bf_bits(float x) {
    bf16 h = __float2bfloat16(x);
    union { bf16 b; unsigned short u; } cv;
    cv.b = h;
    return cv.u;
}

__device__ __forceinline__ float softplus_f(float x) {
    return fmaxf(x, 0.f) + log1pf(expf(-fabsf(x)));
}
// fast silu
__device__ __forceinline__ float silu_f(float x) {
    return x * __builtin_amdgcn_rcpf(1.f + fexp2(-x * LOG2E));
}

// async 16B global -> LDS
__device__ __forceinline__ void gload16(const void* g, void* l) {
    __builtin_amdgcn_global_load_lds(
        (const __attribute__((address_space(1))) void*)g,
        (__attribute__((address_space(3))) void*)l, 16, 0, 0);
}

// ---------- prep: block 0 = dtype detect; blocks 1.. zero xd ----------
__global__ __launch_bounds__(256) void prep_kernel(const unsigned short* hs, int* flag,
                                                   float* zbuf, int nzero) {
    if (blockIdx.x == 0) {
        __shared__ int cnt[256];
        int c = 0;
        for (int i = threadIdx.x; i < 8192; i += 256) {
            int e = (hs[i] >> 7) & 0xFF;
            if (e == 0 || e == 0xFF || e < 96 || e > 159) c++;
        }
        cnt[threadIdx.x] = c;
        __syncthreads();
        for (int s = 128; s > 0; s >>= 1) {
            if (threadIdx.x < s) cnt[threadIdx.x] += cnt[threadIdx.x + s];
            __syncthreads();
        }
        if (threadIdx.x == 0) *flag = (cnt[0] < 512) ? 1 : 0;
    } else {
        int i = (blockIdx.x - 1) * 256 + threadIdx.x;
        if (i < nzero) zbuf[i] = 0.f;
    }
}

// ---------- fused convert of all 10 inputs to one contiguous bf16 arena ----------
// When flag==1 (inputs already bf16), the 3 big segments (0=hs, 1=in_proj, 9=out_proj)
// are skipped: consumers read d_in directly via alt pointers.
struct SrcPtrs { const void* p[10]; };

__device__ __constant__ const size_t SEG_OFF[11] = {
    0, 2097152, 6291456, 6299648, 6301696, 6498304,
    6629376, 6631424, 6664192, 6666240, 8763392
};

__global__ __launch_bounds__(256) void convert_all(SrcPtrs s, bf16* __restrict__ dst,
                                                   const int* __restrict__ flag) {
    size_t e = ((size_t)blockIdx.x * 256 + threadIdx.x) * 4;
    if (e >= SEG_OFF[10]) return;
    int seg = 0;
    #pragma unroll
    for (int i = 1; i < 10; ++i) if (e >= SEG_OFF[i]) seg = i;
    int isbf = *flag;
    if (isbf && (seg == 0 || seg == 1 || seg == 9)) return;  // big segs read direct
    size_t loc = e - SEG_OFF[seg];
    if (isbf) {
        ushort4 v = ((const ushort4*)s.p[seg])[loc / 4];
        ((ushort4*)(dst + e))[0] = v;
    } else {
        float4 v = ((const float4*)s.p[seg])[loc / 4];
        ushort4 o;
        o.x = bf_bits(v.x); o.y = bf_bits(v.y);
        o.z = bf_bits(v.z); o.w = bf_bits(v.w);
        ((ushort4*)(dst + e))[0] = o;
    }
}

// ---------------- MFMA GEMM: C[m][n] = sum_k A[m][k]*B[n][k], bf16 in, 128x128 tile ----
// OUTMODE: 0 = bf16 store
//          2 = f32 store at C + blockIdx.z*pstride (split-K partials)
//          3 = f32 atomicAdd, store only col < 96 (x_proj)
//          4 = f32 store of softplus(v + bias[row]) (dt_proj -> deltaT)
// Aalt/Balt + flag: device-side pointer swap (read d_in directly when bf16).
template <int OUTMODE>
__global__ __launch_bounds__(256) void gemm_mfma(
    const bf16* __restrict__ A, int lda,
    const bf16* __restrict__ Bm, int ldb,
    void* __restrict__ C, int ldc,
    int Kspl, size_t pstride,
    const bf16* __restrict__ bias,
    const bf16* __restrict__ Aalt,
    const bf16* __restrict__ Balt,
    const int* __restrict__ flag)
{
    if (flag && *flag) {
        if (Aalt) A = Aalt;
        if (Balt) Bm = Balt;
    }
    __shared__ __align__(16) __bf16 sA[128 * 32];
    __shared__ __align__(16) __bf16 sB[128 * 32];
    const int tid = threadIdx.x;
    const int m0 = blockIdx.y * 128;
    const int n0 = blockIdx.x * 128;
    const int wid = tid >> 6, ln = tid & 63;
    const int wy = (wid >> 1) * 64, wx = (wid & 1) * 64;
    const int q = ln >> 4, m16 = ln & 15;
    const int kbeg = blockIdx.z * Kspl;

    f32x4 acc[4][4] = {};

    for (int k0 = kbeg; k0 < kbeg + Kspl; k0 += 32) {
        #pragma unroll
        for (int i = 0; i < 2; ++i) {
            int idx = tid + i * 256;
            int r = idx >> 2, c = (idx & 3) * 8;
            gload16(&A[(size_t)(m0 + r) * lda + k0 + c], &sA[idx * 8]);
        }
        #pragma unroll
        for (int i = 0; i < 2; ++i) {
            int idx = tid + i * 256;
            int r = idx >> 2, c = (idx & 3) * 8;
            gload16(&Bm[(size_t)(n0 + r) * ldb + k0 + c], &sB[idx * 8]);
        }
        __syncthreads();
        bf16x8 a[4], b[4];
        #pragma unroll
        for (int i = 0; i < 4; ++i)
            a[i] = *(const bf16x8*)&sA[(wy + i * 16 + m16) * 32 + q * 8];
        #pragma unroll
        for (int j = 0; j < 4; ++j)
            b[j] = *(const bf16x8*)&sB[(wx + j * 16 + m16) * 32 + q * 8];
        #pragma unroll
        for (int i = 0; i < 4; ++i)
            #pragma unroll
            for (int j = 0; j < 4; ++j)
                acc[i][j] = __builtin_amdgcn_mfma_f32_16x16x32_bf16(a[i], b[j], acc[i][j], 0, 0, 0);
        __syncthreads();
    }

    #pragma unroll
    for (int i = 0; i < 4; ++i) {
        #pragma unroll
        for (int j = 0; j < 4; ++j) {
            #pragma unroll
            for (int r = 0; r < 4; ++r) {
                int row = m0 + wy + i * 16 + q * 4 + r;
                int col = n0 + wx + j * 16 + m16;
                size_t idx = (size_t)row * ldc + col;
                float v = acc[i][j][r];
                if constexpr (OUTMODE == 0) {
                    ((bf16*)C)[idx] = __float2bfloat16(v);
                } else if constexpr (OUTMODE == 2) {
                    ((float*)C + blockIdx.z * pstride)[idx] = v;
                } else if constexpr (OUTMODE == 3) {
                    if (col < 96) atomicAdd((float*)C + idx, v);
                } else if constexpr (OUTMODE == 4) {
                    ((float*)C)[idx] = softplus_f(v + to_f(bias[row]));
                }
            }
        }
    }
}

// sum the two split-K partials, store to d_out as bf16 or f32 per flag
__global__ __launch_bounds__(256) void sum_store(
    const float* __restrict__ p0, const float* __restrict__ p1,
    void* __restrict__ out, const int* __restrict__ flag, int n4)
{
    int i = blockIdx.x * 256 + threadIdx.x;
    if (i >= n4) return;
    float4 a = ((const float4*)p0)[i];
    float4 b = ((const float4*)p1)[i];
    float4 sv; sv.x = a.x + b.x; sv.y = a.y + b.y; sv.z = a.z + b.z; sv.w = a.w + b.w;
    if (*flag) {
        ushort4 o;
        o.x = bf_bits(sv.x); o.y = bf_bits(sv.y);
        o.z = bf_bits(sv.z); o.w = bf_bits(sv.w);
        ((ushort4*)out)[i] = o;
    } else {
        ((float4*)out)[i] = sv;
    }
}

// ---------------- transpose utT (d,row) -> ut (row,d), 64x64 LDS tiles ----------------
__global__ __launch_bounds__(256) void transpose_bf16(
    const ushort* __restrict__ src,   // (DINNER, ROWS)
    ushort* __restrict__ dst)         // (ROWS, DINNER)
{
    __shared__ ushort t[64][65];
    const int bx = blockIdx.x;        // row-tile
    const int by = blockIdx.y;        // d-tile
    const int tid = threadIdx.x;
    const int lr = tid & 63;
    const int ld = tid >> 6;          // 0..3
    #pragma unroll
    for (int i = 0; i < 16; ++i) {
        int d = ld + i * 4;
        t[d][lr] = src[(size_t)(by * 64 + d) * ROWS + bx * 64 + lr];
    }
    __syncthreads();
    #pragma unroll
    for (int i = 0; i < 16; ++i) {
        int r = ld + i * 4;
        dst[(size_t)(bx * 64 + r) * DINNER + by * 64 + lr] = t[lr][r];
    }
}

// ---------------- xd post: xd (2048,96) f32 -> xdT (96,2048) f32 + xd_bf bf16 ----------
__global__ __launch_bounds__(256) void xd_post(
    const float* __restrict__ xd,
    float* __restrict__ xdT,
    bf16* __restrict__ xd_bf)
{
    __shared__ float t[96][65];
    const int row0 = blockIdx.x * 64;
    const int tid = threadIdx.x;
    for (int i = tid; i < 64 * 96; i += 256) {
        int row = i / 96, r = i - row * 96;
        float v = xd[(size_t)(row0 + row) * 96 + r];
        t[r][row] = v;
        xd_bf[(size_t)(row0 + row) * 96 + r] = __float2bfloat16(v);
    }
    __syncthreads();
    for (int i = tid; i < 96 * 64; i += 256) {
        int r = i >> 6, row = i & 63;
        xdT[(size_t)r * ROWS + row0 + row] = t[r][row];
    }
}

// ---------------- conv: 8 outputs per thread along L ----------------
__global__ __launch_bounds__(256) void conv_silu_T8(
    const bf16* __restrict__ xzT,
    const bf16* __restrict__ w,
    const bf16* __restrict__ bias,
    bf16* __restrict__ utT)
{
    int t = blockIdx.x * 256 + threadIdx.x;
    int r0 = (t * 8) & (ROWS - 1);
    int d = t >> 8;

    const ushort* xp = (const ushort*)xzT + (size_t)d * ROWS + r0;
    float x[11];
    us8 cur = *(const us8*)xp;
    #pragma unroll
    for (int j = 0; j < 8; ++j) x[3 + j] = bfu(cur[j]);
    if ((r0 & (SEQLEN - 1)) != 0) {
        ushort4 pv = *(const ushort4*)(xp - 4);
        x[0] = bfu(pv.y); x[1] = bfu(pv.z); x[2] = bfu(pv.w);
    } else {
        x[0] = x[1] = x[2] = 0.f;
    }

    ushort4 wv = *(const ushort4*)((const ushort*)w + d * 4);
    float w0 = bfu(wv.x), w1 = bfu(wv.y), w2 = bfu(wv.z), w3 = bfu(wv.w);
    float bv = to_f(bias[d]);

    us8 o;
    #pragma unroll
    for (int j = 0; j < 8; ++j) {
        float acc = bv;
        acc = fmaf(x[j],     w0, acc);
        acc = fmaf(x[j + 1], w1, acc);
        acc = fmaf(x[j + 2], w2, acc);
        acc = fmaf(x[j + 3], w3, acc);
        o[j] = bf_bits(silu_f(acc));
    }
    *(us8*)((ushort*)utT + (size_t)d * ROWS + r0) = o;
}

// ---------------- scan v9: distance-2 rotating prefetch ----------------
// Block = 1024 thr = 16 L-chunks(waves) x 4 d x 16 n. __launch_bounds__(1024, 8)
// pins VGPR <= 64 so 2 blocks/CU (32 waves) stay resident.
#define SCHUNK 16
#define SSTEPS (SEQLEN / SCHUNK)   // 64
__global__ __launch_bounds__(1024, 8) void scan_kernel9(
    const float* __restrict__ deltaT,  // (DINNER, ROWS) f32
    const bf16*  __restrict__ utT,     // (DINNER, ROWS)
    const float* __restrict__ xdT,     // (96, ROWS): row 64+n = B_n, 80+n = C_n
    const bf16*  __restrict__ xzT,     // (4096, ROWS): z at row DINNER+d
    const bf16*  __restrict__ A_log,   // (DINNER,16)
    const bf16*  __restrict__ Dp,      // (DINNER,)
    bf16* __restrict__ outz)           // (ROWS, DINNER)
{
    __shared__ float sH[SCHUNK][64], sP[SCHUNK][64];
    const int tid = threadIdx.x;
    const int c = tid >> 6;
    const int w = tid & 63;
    const int n = tid & 15;
    const int b = blockIdx.x >> 9;
    const int d = ((blockIdx.x & 511) << 2) + ((tid >> 4) & 3);
    const int row0 = b * SEQLEN + c * SSTEPS;

    const float Aa2 = -expf(to_f(A_log[d * DSTATE + n])) * LOG2E;
    const float Dv16 = to_f(Dp[d]) * (1.f / 16.f);

    const float*  dp = deltaT + (size_t)d * ROWS + row0;
    const ushort* up = (const ushort*)utT + (size_t)d * ROWS + row0;
    const ushort* zp = (const ushort*)xzT + (size_t)(DINNER + d) * ROWS + row0;
    const float*  Bp = xdT + (size_t)(64 + n) * ROWS + row0;
    const float*  Cp = xdT + (size_t)(80 + n) * ROWS + row0;

    // ---- phase 1: local scan, distance-2 rotating prefetch ----
    float h = 0.f, sd = 0.f;
    {
        float4  d0 = *(const float4*)(dp);
        ushort4 u0 = *(const ushort4*)(up);
        float4  B0 = *(const float4*)(Bp);
        float4  d1 = *(const float4*)(dp + 4);
        ushort4 u1 = *(const ushort4*)(up + 4);
        float4  B1 = *(const float4*)(Bp + 4);
        for (int i0 = 0; i0 < SSTEPS; i0 += 4) {
            float4 dvc = d0; ushort4 uvc = u0; float4 Bvc = B0;
            d0 = d1; u0 = u1; B0 = B1;
            if (i0 + 8 < SSTEPS) {
                d1 = *(const float4*)(dp + i0 + 8);
                u1 = *(const ushort4*)(up + i0 + 8);
                B1 = *(const float4*)(Bp + i0 + 8);
            }
            float dv[4] = {dvc.x, dvc.y, dvc.z, dvc.w};
            float uv[4] = {bfu(uvc.x), bfu(uvc.y), bfu(uvc.z), bfu(uvc.w)};
            float Bv[4] = {Bvc.x, Bvc.y, Bvc.z, Bvc.w};
            #pragma unroll
            for (int j = 0; j < 4; ++j) {
                float a = fexp2(dv[j] * Aa2);
                h = fmaf(a, h, dv[j] * Bv[j] * uv[j]);
                sd += dv[j];
            }
        }
    }
    sH[c][w] = h;
    sP[c][w] = fexp2(sd * Aa2);
    __syncthreads();

    // ---- phase 2: fold preceding chunk summaries ----
    float hin = 0.f;
    for (int cc = 0; cc < c; ++cc)
        hin = fmaf(sP[cc][w], hin, sH[cc][w]);

    // ---- phase 3: rescan, distance-2 rotating prefetch, batched epilogue ----
    h = hin;
    {
        float4  d0 = *(const float4*)(dp);
        ushort4 u0 = *(const ushort4*)(up);
        float4  B0 = *(const float4*)(Bp);
        float4  C0 = *(const float4*)(Cp);
        ushort4 z0 = *(const ushort4*)(zp);
        float4  d1 = *(const float4*)(dp + 4);
        ushort4 u1 = *(const ushort4*)(up + 4);
        float4  B1 = *(const float4*)(Bp + 4);
        float4  C1 = *(const float4*)(Cp + 4);
        ushort4 z1 = *(const ushort4*)(zp + 4);
        for (int i0 = 0; i0 < SSTEPS; i0 += 4) {
            float4 dvc = d0; ushort4 uvc = u0; float4 Bvc = B0;
            float4 Cvc = C0; ushort4 zvc = z0;
            d0 = d1; u0 = u1; B0 = B1; C0 = C1; z0 = z1;
            if (i0 + 8 < SSTEPS) {
                d1 = *(const float4*)(dp + i0 + 8);
                u1 = *(const ushort4*)(up + i0 + 8);
                B1 = *(const float4*)(Bp + i0 + 8);
                C1 = *(const float4*)(Cp + i0 + 8);
                z1 = *(const ushort4*)(zp + i0 + 8);
            }
            float dv[4] = {dvc.x, dvc.y, dvc.z, dvc.w};
            float uv[4] = {bfu(uvc.x), bfu(uvc.y), bfu(uvc.z), bfu(uvc.w)};
            float Bv[4] = {Bvc.x, Bvc.y, Bvc.z, Bvc.w};
            float Cv[4] = {Cvc.x, Cvc.y, Cvc.z, Cvc.w};
            float zv[4] = {bfu(zvc.x), bfu(zvc.y), bfu(zvc.z), bfu(zvc.w)};
            float y[4];
            #pragma unroll
            for (int j = 0; j < 4; ++j) {
                float a = fexp2(dv[j] * Aa2);
                h = fmaf(a, h, dv[j] * Bv[j] * uv[j]);
                float p = fmaf(uv[j], Dv16, h * Cv[j]);
                p += __shfl_xor(p, 1, 16);
                p += __shfl_xor(p, 2, 16);
                p += __shfl_xor(p, 4, 16);
                p += __shfl_xor(p, 8, 16);
                y[j] = p;
            }
            float t0 = (n & 4) ? y[1] : y[0];
            float t1 = (n & 4) ? y[3] : y[2];
            float yv = (n & 8) ? t1 : t0;
            float za = (n & 4) ? zv[1] : zv[0];
            float zb = (n & 4) ? zv[3] : zv[2];
            float zz = (n & 8) ? zb : za;
            if ((n & 3) == 0) {
                int q2 = n >> 2;
                outz[(size_t)(row0 + i0 + q2) * DINNER + d] =
                    __float2bfloat16(yv * silu_f(zz));
            }
        }
    }
}

extern "C" void kernel_launch(void* const* d_in, const int* in_sizes, int n_in,
                              void* d_out, int out_size, void* d_ws, size_t ws_size,
                              hipStream_t stream) {
    static const size_t SZ[10] = {
        (size_t)BATCH * SEQLEN * DMODEL,        // hidden_states
        (size_t)2 * DINNER * DMODEL,            // in_proj_w
        (size_t)DINNER * 4,                     // conv1d_w
        (size_t)DINNER,                         // conv1d_b
        (size_t)(DTRANK + 2 * DSTATE) * DINNER, // x_proj_w
        (size_t)DINNER * DTRANK,                // dt_proj_w
        (size_t)DINNER,                         // dt_proj_b
        (size_t)DINNER * DSTATE,                // A_log
        (size_t)DINNER,                         // D_param
        (size_t)DMODEL * DINNER                 // out_proj_w
    };
    size_t tot_in = 0;
    for (int i = 0; i < 10; ++i) tot_in += SZ[i];

    char* p = (char*)d_ws;
    int* flag = (int*)p;                     p += 64;
    bf16* inb = (bf16*)p;                    p += tot_in * 2;
    bf16* xzT = (bf16*)p;                    p += (size_t)4096 * ROWS * 2;
    bf16* utT = (bf16*)p;                    p += (size_t)DINNER * ROWS * 2;
    bf16* ut  = (bf16*)p;                    p += (size_t)ROWS * DINNER * 2;
    float* xd = (float*)p;                   p += (size_t)ROWS * 96 * 4;
    bf16* xd_bf = (bf16*)p;                  p += (size_t)ROWS * 96 * 2;
    float* xdT = (float*)p;                  p += (size_t)96 * ROWS * 4;
    float* deltaT = (float*)p;               p += (size_t)DINNER * ROWS * 4;
    bf16* outz = (bf16*)p;                   p += (size_t)ROWS * DINNER * 2;
    float* part = (float*)p;                 p += (size_t)2 * ROWS * DMODEL * 4;
    size_t needed = (size_t)(p - (char*)d_ws);
    if (ws_size < needed) return;

    dim3 blk(256);

    // 0) detect dtype + zero xd (for atomic accumulation)
    prep_kernel<<<1 + (ROWS * 96 + 255) / 256, blk, 0, stream>>>(
        (const unsigned short*)d_in[0], flag, xd, ROWS * 96);

    bf16* inp[10];
    {
        size_t off = 0;
        for (int i = 0; i < 10; ++i) { inp[i] = inb + off; off += SZ[i]; }
    }
    SrcPtrs sp;
    for (int i = 0; i < 10; ++i) sp.p[i] = d_in[i];
    convert_all<<<(int)((tot_in / 4 + 255) / 256), blk, 0, stream>>>(sp, inb, flag);

    const bf16* hs        = inp[0];
    const bf16* in_proj_w = inp[1];
    const bf16* conv_w    = inp[2];
    const bf16* conv_b    = inp[3];
    const bf16* x_proj_w  = inp[4];
    const bf16* dt_proj_w = inp[5];
    const bf16* dt_proj_b = inp[6];
    const bf16* A_log     = inp[7];
    const bf16* Dp        = inp[8];
    const bf16* out_proj_w= inp[9];

    // 1) xzT = (hs @ in_proj_w^T)^T : dual-ptr — reads d_in directly when bf16
    gemm_mfma<0><<<dim3(ROWS / 128, 4096 / 128, 1), blk, 0, stream>>>(
        in_proj_w, DMODEL, hs, DMODEL, xzT, ROWS, DMODEL, 0, nullptr,
        (const bf16*)d_in[1], (const bf16*)d_in[0], flag);

    // 2) utT = silu(causal depthwise conv along L), d-major
    conv_silu_T8<<<(DINNER * ROWS / 8) / 256, blk, 0, stream>>>(xzT, conv_w, conv_b, utT);

    // 2b) ut = utT^T (row-major, for MFMA x_proj)
    transpose_bf16<<<dim3(ROWS / 64, DINNER / 64), blk, 0, stream>>>(
        (const ushort*)utT, (ushort*)ut);

    // 3) xd[row][r] = sum_d ut[row][d] * x_proj_w[r][d]  (MFMA, split-K=4, atomic f32)
    gemm_mfma<3><<<dim3(1, ROWS / 128, 4), blk, 0, stream>>>(
        ut, DINNER, x_proj_w, DINNER, xd, 96, DINNER / 4, 0, nullptr,
        nullptr, nullptr, nullptr);

    // 3b) xdT = xd^T (f32, scan layout) + xd_bf (bf16 row-major, dt GEMM operand)
    xd_post<<<ROWS / 64, blk, 0, stream>>>(xd, xdT, xd_bf);

    // 4) deltaT[d][row] = softplus(sum_r dtw[d][r]*xd[row][r] + dtb[d])  (MFMA K=64)
    gemm_mfma<4><<<dim3(ROWS / 128, DINNER / 128, 1), blk, 0, stream>>>(
        dt_proj_w, DTRANK, xd_bf, 96, deltaT, ROWS, DTRANK, 0, dt_proj_b,
        nullptr, nullptr, nullptr);

    // 5) chunk-parallel selective scan (distance-2 prefetch) -> outz (row-major)
    scan_kernel9<<<BATCH * (DINNER / 4), dim3(1024), 0, stream>>>(
        deltaT, utT, xdT, xzT, A_log, Dp, outz);

    // 6) out = outz @ out_proj_w^T  (MFMA split-K=2 -> f32 partials; dual-ptr B)
    gemm_mfma<2><<<dim3(DMODEL / 128, ROWS / 128, 2), blk, 0, stream>>>(
        outz, DINNER, out_proj_w, DINNER, part, DMODEL, DINNER / 2, (size_t)ROWS * DMODEL,
        nullptr, nullptr, (const bf16*)d_in[9], flag);

    // 6b) out = cvt(part0 + part1)
    sum_store<<<(ROWS * DMODEL / 4 + 255) / 256, blk, 0, stream>>>(
        part, part + (size_t)ROWS * DMODEL, d_out, flag, ROWS * DMODEL / 4);
}

// Round 13
// 345.662 us; speedup vs baseline: 1.1530x; 1.1530x over previous
//
#include <hip/hip_runtime.h>
#include <hip/hip_bf16.h>

// Shapes: B=2, L=1024, D_MODEL=1024, D_INNER=2048, D_STATE=16, D_CONV=4, DT_RANK=64
#define BATCH 2
#define SEQLEN 1024
#define DMODEL 1024
#define DINNER 2048
#define DSTATE 16
#define DTRANK 64
#define ROWS (BATCH * SEQLEN) // 2048
#define LOG2E 1.44269504088896340736f

using bf16 = __hip_bfloat16;
typedef __bf16 bf16x8 __attribute__((ext_vector_type(8)));
typedef float f32x4 __attribute__((ext_vector_type(4)));
typedef unsigned short us8 __attribute__((ext_vector_type(8)));

__device__ __forceinline__ float to_f(float x) { return x; }
__device__ __forceinline__ float to_f(bf16 x) { return __bfloat162float(x); }

__device__ __forceinline__ float fexp2(float x) { return __builtin_amdgcn_exp2f(x); }

__device__ __forceinline__ float bfu(unsigned short u) {
    union { unsigned int i; float f; } v;
    v.i = ((unsigned int)u) << 16;
    return v.f;
}

__device__ __forceinline__ unsigned short bf_bits(float x) {
    bf16 h = __float2bfloat16(x);
    union { bf16 b; unsigned short u; } cv;
    cv.b = h;
    return cv.u;
}

__device__ __forceinline__ float softplus_f(float x) {
    return fmaxf(x, 0.f) + log1pf(expf(-fabsf(x)));
}
// fast silu
__device__ __forceinline__ float silu_f(float x) {
    return x * __builtin_amdgcn_rcpf(1.f + fexp2(-x * LOG2E));
}

// async 16B global -> LDS
__device__ __forceinline__ void gload16(const void* g, void* l) {
    __builtin_amdgcn_global_load_lds(
        (const __attribute__((address_space(1))) void*)g,
        (__attribute__((address_space(3))) void*)l, 16, 0, 0);
}

// ---------- prep: block 0 = dtype detect; blocks 1.. zero xd ----------
__global__ __launch_bounds__(256) void prep_kernel(const unsigned short* hs, int* flag,
                                                   float* zbuf, int nzero) {
    if (blockIdx.x == 0) {
        __shared__ int cnt[256];
        int c = 0;
        for (int i = threadIdx.x; i < 8192; i += 256) {
            int e = (hs[i] >> 7) & 0xFF;
            if (e == 0 || e == 0xFF || e < 96 || e > 159) c++;
        }
        cnt[threadIdx.x] = c;
        __syncthreads();
        for (int s = 128; s > 0; s >>= 1) {
            if (threadIdx.x < s) cnt[threadIdx.x] += cnt[threadIdx.x + s];
            __syncthreads();
        }
        if (threadIdx.x == 0) *flag = (cnt[0] < 512) ? 1 : 0;
    } else {
        int i = (blockIdx.x - 1) * 256 + threadIdx.x;
        if (i < nzero) zbuf[i] = 0.f;
    }
}

// ---------- fused convert; big bf16 segments skipped (read direct) ----------
struct SrcPtrs { const void* p[10]; };

__device__ __constant__ const size_t SEG_OFF[11] = {
    0, 2097152, 6291456, 6299648, 6301696, 6498304,
    6629376, 6631424, 6664192, 6666240, 8763392
};

__global__ __launch_bounds__(256) void convert_all(SrcPtrs s, bf16* __restrict__ dst,
                                                   const int* __restrict__ flag) {
    size_t e = ((size_t)blockIdx.x * 256 + threadIdx.x) * 4;
    if (e >= SEG_OFF[10]) return;
    int seg = 0;
    #pragma unroll
    for (int i = 1; i < 10; ++i) if (e >= SEG_OFF[i]) seg = i;
    int isbf = *flag;
    if (isbf && (seg == 0 || seg == 1 || seg == 9)) return;
    size_t loc = e - SEG_OFF[seg];
    if (isbf) {
        ushort4 v = ((const ushort4*)s.p[seg])[loc / 4];
        ((ushort4*)(dst + e))[0] = v;
    } else {
        float4 v = ((const float4*)s.p[seg])[loc / 4];
        ushort4 o;
        o.x = bf_bits(v.x); o.y = bf_bits(v.y);
        o.z = bf_bits(v.z); o.w = bf_bits(v.w);
        ((ushort4*)(dst + e))[0] = o;
    }
}

// ---------------- MFMA GEMM: C[m][n] = sum_k A[m][k]*B[n][k], bf16 in, 128x128 tile ----
// OUTMODE: 0 = bf16 store; 2 = f32 split-K partials; 3 = f32 atomicAdd col<96;
//          4 = f32 softplus(v + bias[row])
template <int OUTMODE>
__global__ __launch_bounds__(256) void gemm_mfma(
    const bf16* __restrict__ A, int lda,
    const bf16* __restrict__ Bm, int ldb,
    void* __restrict__ C, int ldc,
    int Kspl, size_t pstride,
    const bf16* __restrict__ bias,
    const bf16* __restrict__ Aalt,
    const bf16* __restrict__ Balt,
    const int* __restrict__ flag)
{
    if (flag && *flag) {
        if (Aalt) A = Aalt;
        if (Balt) Bm = Balt;
    }
    __shared__ __align__(16) __bf16 sA[128 * 32];
    __shared__ __align__(16) __bf16 sB[128 * 32];
    const int tid = threadIdx.x;
    const int m0 = blockIdx.y * 128;
    const int n0 = blockIdx.x * 128;
    const int wid = tid >> 6, ln = tid & 63;
    const int wy = (wid >> 1) * 64, wx = (wid & 1) * 64;
    const int q = ln >> 4, m16 = ln & 15;
    const int kbeg = blockIdx.z * Kspl;

    f32x4 acc[4][4] = {};

    for (int k0 = kbeg; k0 < kbeg + Kspl; k0 += 32) {
        #pragma unroll
        for (int i = 0; i < 2; ++i) {
            int idx = tid + i * 256;
            int r = idx >> 2, c = (idx & 3) * 8;
            gload16(&A[(size_t)(m0 + r) * lda + k0 + c], &sA[idx * 8]);
        }
        #pragma unroll
        for (int i = 0; i < 2; ++i) {
            int idx = tid + i * 256;
            int r = idx >> 2, c = (idx & 3) * 8;
            gload16(&Bm[(size_t)(n0 + r) * ldb + k0 + c], &sB[idx * 8]);
        }
        __syncthreads();
        bf16x8 a[4], b[4];
        #pragma unroll
        for (int i = 0; i < 4; ++i)
            a[i] = *(const bf16x8*)&sA[(wy + i * 16 + m16) * 32 + q * 8];
        #pragma unroll
        for (int j = 0; j < 4; ++j)
            b[j] = *(const bf16x8*)&sB[(wx + j * 16 + m16) * 32 + q * 8];
        #pragma unroll
        for (int i = 0; i < 4; ++i)
            #pragma unroll
            for (int j = 0; j < 4; ++j)
                acc[i][j] = __builtin_amdgcn_mfma_f32_16x16x32_bf16(a[i], b[j], acc[i][j], 0, 0, 0);
        __syncthreads();
    }

    #pragma unroll
    for (int i = 0; i < 4; ++i) {
        #pragma unroll
        for (int j = 0; j < 4; ++j) {
            #pragma unroll
            for (int r = 0; r < 4; ++r) {
                int row = m0 + wy + i * 16 + q * 4 + r;
                int col = n0 + wx + j * 16 + m16;
                size_t idx = (size_t)row * ldc + col;
                float v = acc[i][j][r];
                if constexpr (OUTMODE == 0) {
                    ((bf16*)C)[idx] = __float2bfloat16(v);
                } else if constexpr (OUTMODE == 2) {
                    ((float*)C + blockIdx.z * pstride)[idx] = v;
                } else if constexpr (OUTMODE == 3) {
                    if (col < 96) atomicAdd((float*)C + idx, v);
                } else if constexpr (OUTMODE == 4) {
                    ((float*)C)[idx] = softplus_f(v + to_f(bias[row]));
                }
            }
        }
    }
}

// sum the two split-K partials, store to d_out as bf16 or f32 per flag
__global__ __launch_bounds__(256) void sum_store(
    const float* __restrict__ p0, const float* __restrict__ p1,
    void* __restrict__ out, const int* __restrict__ flag, int n4)
{
    int i = blockIdx.x * 256 + threadIdx.x;
    if (i >= n4) return;
    float4 a = ((const float4*)p0)[i];
    float4 b = ((const float4*)p1)[i];
    float4 sv; sv.x = a.x + b.x; sv.y = a.y + b.y; sv.z = a.z + b.z; sv.w = a.w + b.w;
    if (*flag) {
        ushort4 o;
        o.x = bf_bits(sv.x); o.y = bf_bits(sv.y);
        o.z = bf_bits(sv.z); o.w = bf_bits(sv.w);
        ((ushort4*)out)[i] = o;
    } else {
        ((float4*)out)[i] = sv;
    }
}

// ---------------- transpose (d,row) -> (row,d), 64x64 LDS tiles ----------------
__global__ __launch_bounds__(256) void transpose_bf16(
    const ushort* __restrict__ src,   // (DINNER, ROWS)
    ushort* __restrict__ dst)         // (ROWS, DINNER)
{
    __shared__ ushort t[64][65];
    const int bx = blockIdx.x;        // row-tile
    const int by = blockIdx.y;        // d-tile
    const int tid = threadIdx.x;
    const int lr = tid & 63;
    const int ld = tid >> 6;          // 0..3
    #pragma unroll
    for (int i = 0; i < 16; ++i) {
        int d = ld + i * 4;
        t[d][lr] = src[(size_t)(by * 64 + d) * ROWS + bx * 64 + lr];
    }
    __syncthreads();
    #pragma unroll
    for (int i = 0; i < 16; ++i) {
        int r = ld + i * 4;
        dst[(size_t)(bx * 64 + r) * DINNER + by * 64 + lr] = t[lr][r];
    }
}

// ---------------- xd post: xd (2048,96) f32 -> xdT (96,2048) f32 + xd_bf bf16 ----------
__global__ __launch_bounds__(256) void xd_post(
    const float* __restrict__ xd,
    float* __restrict__ xdT,
    bf16* __restrict__ xd_bf)
{
    __shared__ float t[96][65];
    const int row0 = blockIdx.x * 64;
    const int tid = threadIdx.x;
    for (int i = tid; i < 64 * 96; i += 256) {
        int row = i / 96, r = i - row * 96;
        float v = xd[(size_t)(row0 + row) * 96 + r];
        t[r][row] = v;
        xd_bf[(size_t)(row0 + row) * 96 + r] = __float2bfloat16(v);
    }
    __syncthreads();
    for (int i = tid; i < 96 * 64; i += 256) {
        int r = i >> 6, row = i & 63;
        xdT[(size_t)r * ROWS + row0 + row] = t[r][row];
    }
}

// ---------------- conv: 8 outputs per thread along L ----------------
__global__ __launch_bounds__(256) void conv_silu_T8(
    const bf16* __restrict__ xzT,
    const bf16* __restrict__ w,
    const bf16* __restrict__ bias,
    bf16* __restrict__ utT)
{
    int t = blockIdx.x * 256 + threadIdx.x;
    int r0 = (t * 8) & (ROWS - 1);
    int d = t >> 8;

    const ushort* xp = (const ushort*)xzT + (size_t)d * ROWS + r0;
    float x[11];
    us8 cur = *(const us8*)xp;
    #pragma unroll
    for (int j = 0; j < 8; ++j) x[3 + j] = bfu(cur[j]);
    if ((r0 & (SEQLEN - 1)) != 0) {
        ushort4 pv = *(const ushort4*)(xp - 4);
        x[0] = bfu(pv.y); x[1] = bfu(pv.z); x[2] = bfu(pv.w);
    } else {
        x[0] = x[1] = x[2] = 0.f;
    }

    ushort4 wv = *(const ushort4*)((const ushort*)w + d * 4);
    float w0 = bfu(wv.x), w1 = bfu(wv.y), w2 = bfu(wv.z), w3 = bfu(wv.w);
    float bv = to_f(bias[d]);

    us8 o;
    #pragma unroll
    for (int j = 0; j < 8; ++j) {
        float acc = bv;
        acc = fmaf(x[j],     w0, acc);
        acc = fmaf(x[j + 1], w1, acc);
        acc = fmaf(x[j + 2], w2, acc);
        acc = fmaf(x[j + 3], w3, acc);
        o[j] = bf_bits(silu_f(acc));
    }
    *(us8*)((ushort*)utT + (size_t)d * ROWS + r0) = o;
}

// ---------------- scan v10: v7 body + d-major vectorized output ----------------
// Block = 1024 thr = 16 L-chunks(waves) x 4 d x 16 n; grid = BATCH * DINNER/4.
// Output outzT (DINNER, ROWS): lane n==0 packs 4 consecutive rows into one
// ushort4 store -> full-line writes, no false sharing, no select tree.
#define SCHUNK 16
#define SSTEPS (SEQLEN / SCHUNK)   // 64
__global__ __launch_bounds__(1024) void scan_kernel10(
    const float* __restrict__ deltaT,  // (DINNER, ROWS) f32
    const bf16*  __restrict__ utT,     // (DINNER, ROWS)
    const float* __restrict__ xdT,     // (96, ROWS): row 64+n = B_n, 80+n = C_n
    const bf16*  __restrict__ xzT,     // (4096, ROWS): z at row DINNER+d
    const bf16*  __restrict__ A_log,   // (DINNER,16)
    const bf16*  __restrict__ Dp,      // (DINNER,)
    bf16* __restrict__ outzT)          // (DINNER, ROWS)
{
    __shared__ float sH[SCHUNK][64], sP[SCHUNK][64];
    const int tid = threadIdx.x;
    const int c = tid >> 6;
    const int w = tid & 63;
    const int n = tid & 15;
    const int b = blockIdx.x >> 9;
    const int d = ((blockIdx.x & 511) << 2) + ((tid >> 4) & 3);
    const int row0 = b * SEQLEN + c * SSTEPS;

    const float Aa2 = -expf(to_f(A_log[d * DSTATE + n])) * LOG2E;
    const float Dv16 = to_f(Dp[d]) * (1.f / 16.f);

    const float*  dp = deltaT + (size_t)d * ROWS + row0;
    const ushort* up = (const ushort*)utT + (size_t)d * ROWS + row0;
    const ushort* zp = (const ushort*)xzT + (size_t)(DINNER + d) * ROWS + row0;
    const float*  Bp = xdT + (size_t)(64 + n) * ROWS + row0;
    const float*  Cp = xdT + (size_t)(80 + n) * ROWS + row0;

    // phase 1: local scan; decay product via sum-of-delta + one exp2
    float h = 0.f, sd = 0.f;
    for (int i0 = 0; i0 < SSTEPS; i0 += 4) {
        float4  dv4 = *(const float4*)(dp + i0);
        ushort4 uv4 = *(const ushort4*)(up + i0);
        float4  Bv4 = *(const float4*)(Bp + i0);
        float dv[4] = {dv4.x, dv4.y, dv4.z, dv4.w};
        float uv[4] = {bfu(uv4.x), bfu(uv4.y), bfu(uv4.z), bfu(uv4.w)};
        float Bv[4] = {Bv4.x, Bv4.y, Bv4.z, Bv4.w};
        #pragma unroll
        for (int j = 0; j < 4; ++j) {
            float a = fexp2(dv[j] * Aa2);
            h = fmaf(a, h, dv[j] * Bv[j] * uv[j]);
            sd += dv[j];
        }
    }
    sH[c][w] = h;
    sP[c][w] = fexp2(sd * Aa2);
    __syncthreads();

    // phase 2: fold preceding chunk summaries
    float hin = 0.f;
    for (int cc = 0; cc < c; ++cc)
        hin = fmaf(sP[cc][w], hin, sH[cc][w]);

    // phase 3: rescan; packed 4-row store from lane n==0
    h = hin;
    for (int i0 = 0; i0 < SSTEPS; i0 += 4) {
        float4  dv4 = *(const float4*)(dp + i0);
        ushort4 uv4 = *(const ushort4*)(up + i0);
        float4  Bv4 = *(const float4*)(Bp + i0);
        float4  Cv4 = *(const float4*)(Cp + i0);
        ushort4 zv4 = *(const ushort4*)(zp + i0);
        float dv[4] = {dv4.x, dv4.y, dv4.z, dv4.w};
        float uv[4] = {bfu(uv4.x), bfu(uv4.y), bfu(uv4.z), bfu(uv4.w)};
        float Bv[4] = {Bv4.x, Bv4.y, Bv4.z, Bv4.w};
        float Cv[4] = {Cv4.x, Cv4.y, Cv4.z, Cv4.w};
        float zv[4] = {bfu(zv4.x), bfu(zv4.y), bfu(zv4.z), bfu(zv4.w)};
        float y[4];
        #pragma unroll
        for (int j = 0; j < 4; ++j) {
            float a = fexp2(dv[j] * Aa2);
            h = fmaf(a, h, dv[j] * Bv[j] * uv[j]);
            float p = fmaf(uv[j], Dv16, h * Cv[j]);
            p += __shfl_xor(p, 1, 16);
            p += __shfl_xor(p, 2, 16);
            p += __shfl_xor(p, 4, 16);
            p += __shfl_xor(p, 8, 16);
            y[j] = p;
        }
        if (n == 0) {
            ushort4 o;
            o.x = bf_bits(y[0] * silu_f(zv[0]));
            o.y = bf_bits(y[1] * silu_f(zv[1]));
            o.z = bf_bits(y[2] * silu_f(zv[2]));
            o.w = bf_bits(y[3] * silu_f(zv[3]));
            *(ushort4*)((ushort*)outzT + (size_t)d * ROWS + row0 + i0) = o;
        }
    }
}

extern "C" void kernel_launch(void* const* d_in, const int* in_sizes, int n_in,
                              void* d_out, int out_size, void* d_ws, size_t ws_size,
                              hipStream_t stream) {
    static const size_t SZ[10] = {
        (size_t)BATCH * SEQLEN * DMODEL,        // hidden_states
        (size_t)2 * DINNER * DMODEL,            // in_proj_w
        (size_t)DINNER * 4,                     // conv1d_w
        (size_t)DINNER,                         // conv1d_b
        (size_t)(DTRANK + 2 * DSTATE) * DINNER, // x_proj_w
        (size_t)DINNER * DTRANK,                // dt_proj_w
        (size_t)DINNER,                         // dt_proj_b
        (size_t)DINNER * DSTATE,                // A_log
        (size_t)DINNER,                         // D_param
        (size_t)DMODEL * DINNER                 // out_proj_w
    };
    size_t tot_in = 0;
    for (int i = 0; i < 10; ++i) tot_in += SZ[i];

    char* p = (char*)d_ws;
    int* flag = (int*)p;                     p += 64;
    bf16* inb = (bf16*)p;                    p += tot_in * 2;
    bf16* xzT = (bf16*)p;                    p += (size_t)4096 * ROWS * 2;
    bf16* utT = (bf16*)p;                    p += (size_t)DINNER * ROWS * 2;
    bf16* ut  = (bf16*)p;                    p += (size_t)ROWS * DINNER * 2;
    float* xd = (float*)p;                   p += (size_t)ROWS * 96 * 4;
    bf16* xd_bf = (bf16*)p;                  p += (size_t)ROWS * 96 * 2;
    float* xdT = (float*)p;                  p += (size_t)96 * ROWS * 4;
    float* deltaT = (float*)p;               p += (size_t)DINNER * ROWS * 4;
    bf16* outzT = (bf16*)p;                  p += (size_t)DINNER * ROWS * 2;
    bf16* outz = (bf16*)p;                   p += (size_t)ROWS * DINNER * 2;
    float* part = (float*)p;                 p += (size_t)2 * ROWS * DMODEL * 4;
    size_t needed = (size_t)(p - (char*)d_ws);
    if (ws_size < needed) return;

    dim3 blk(256);

    // 0) detect dtype + zero xd (for atomic accumulation)
    prep_kernel<<<1 + (ROWS * 96 + 255) / 256, blk, 0, stream>>>(
        (const unsigned short*)d_in[0], flag, xd, ROWS * 96);

    bf16* inp[10];
    {
        size_t off = 0;
        for (int i = 0; i < 10; ++i) { inp[i] = inb + off; off += SZ[i]; }
    }
    SrcPtrs sp;
    for (int i = 0; i < 10; ++i) sp.p[i] = d_in[i];
    convert_all<<<(int)((tot_in / 4 + 255) / 256), blk, 0, stream>>>(sp, inb, flag);

    const bf16* hs        = inp[0];
    const bf16* in_proj_w = inp[1];
    const bf16* conv_w    = inp[2];
    const bf16* conv_b    = inp[3];
    const bf16* x_proj_w  = inp[4];
    const bf16* dt_proj_w = inp[5];
    const bf16* dt_proj_b = inp[6];
    const bf16* A_log     = inp[7];
    const bf16* Dp        = inp[8];
    const bf16* out_proj_w= inp[9];

    // 1) xzT = (hs @ in_proj_w^T)^T : dual-ptr — reads d_in directly when bf16
    gemm_mfma<0><<<dim3(ROWS / 128, 4096 / 128, 1), blk, 0, stream>>>(
        in_proj_w, DMODEL, hs, DMODEL, xzT, ROWS, DMODEL, 0, nullptr,
        (const bf16*)d_in[1], (const bf16*)d_in[0], flag);

    // 2) utT = silu(causal depthwise conv along L), d-major
    conv_silu_T8<<<(DINNER * ROWS / 8) / 256, blk, 0, stream>>>(xzT, conv_w, conv_b, utT);

    // 2b) ut = utT^T (row-major, for MFMA x_proj)
    transpose_bf16<<<dim3(ROWS / 64, DINNER / 64), blk, 0, stream>>>(
        (const ushort*)utT, (ushort*)ut);

    // 3) xd[row][r] = sum_d ut[row][d] * x_proj_w[r][d]  (MFMA, split-K=4, atomic f32)
    gemm_mfma<3><<<dim3(1, ROWS / 128, 4), blk, 0, stream>>>(
        ut, DINNER, x_proj_w, DINNER, xd, 96, DINNER / 4, 0, nullptr,
        nullptr, nullptr, nullptr);

    // 3b) xdT = xd^T (f32, scan layout) + xd_bf (bf16 row-major, dt GEMM operand)
    xd_post<<<ROWS / 64, blk, 0, stream>>>(xd, xdT, xd_bf);

    // 4) deltaT[d][row] = softplus(sum_r dtw[d][r]*xd[row][r] + dtb[d])  (MFMA K=64)
    gemm_mfma<4><<<dim3(ROWS / 128, DINNER / 128, 1), blk, 0, stream>>>(
        dt_proj_w, DTRANK, xd_bf, 96, deltaT, ROWS, DTRANK, 0, dt_proj_b,
        nullptr, nullptr, nullptr);

    // 5) chunk-parallel selective scan -> outzT (d-major, full-line writes)
    scan_kernel10<<<BATCH * (DINNER / 4), dim3(1024), 0, stream>>>(
        deltaT, utT, xdT, xzT, A_log, Dp, outzT);

    // 5b) outz = outzT^T (row-major for gemm6)
    transpose_bf16<<<dim3(ROWS / 64, DINNER / 64), blk, 0, stream>>>(
        (const ushort*)outzT, (ushort*)outz);

    // 6) out = outz @ out_proj_w^T  (MFMA split-K=2 -> f32 partials; dual-ptr B)
    gemm_mfma<2><<<dim3(DMODEL / 128, ROWS / 128, 2), blk, 0, stream>>>(
        outz, DINNER, out_proj_w, DINNER, part, DMODEL, DINNER / 2, (size_t)ROWS * DMODEL,
        nullptr, nullptr, (const bf16*)d_in[9], flag);

    // 6b) out = cvt(part0 + part1)
    sum_store<<<(ROWS * DMODEL / 4 + 255) / 256, blk, 0, stream>>>(
        part, part + (size_t)ROWS * DMODEL, d_out, flag, ROWS * DMODEL / 4);
}